// Round 13
// baseline (156.673 us; speedup 1.0000x reference)
//
#include <hip/hip_runtime.h>
#include <hip/hip_bf16.h>
#include <cstddef>

// Problem constants: B=1, L=256, D=128, H=4, hd=32
#define DD 128

typedef unsigned short u16;
typedef short short8v __attribute__((ext_vector_type(8)));    // 8 bf16 (4 VGPRs)
typedef float floatx4 __attribute__((ext_vector_type(4)));    // 4 fp32 acc
typedef float floatx16 __attribute__((ext_vector_type(16)));  // 16 fp32 acc (32x32)

__device__ __forceinline__ float bf2f(u16 u) {
    return __uint_as_float(((unsigned int)u) << 16);
}
__device__ __forceinline__ u16 f2b(float x) {   // round-to-nearest-even f32->bf16
    unsigned u = __float_as_uint(x);
    return (u16)((u + 0x7FFF + ((u >> 16) & 1)) >> 16);
}
__device__ __forceinline__ unsigned cvtpk_bf16(float lo, float hi) {
    unsigned r;
    asm("v_cvt_pk_bf16_f32 %0, %1, %2" : "=v"(r) : "v"(lo), "v"(hi));
    return r;
}

// Repack a 32x32 MFMA D-tile (lane=col, 16 rows at (rr&3)+8*(rr>>2)+4*hi) into two
// operand fragments (lane-local rows 8hi..8hi+7 per 16-row half) -- verified
// cvt_pk + permlane32_swap algebra (same as the attention P repack).
__device__ __forceinline__ void repack16(const floatx16& a, short8v& f0, short8v& f1) {
    unsigned u[8];
    #pragma unroll
    for (int e = 0; e < 4; ++e) {
        u[2*e]   = cvtpk_bf16(a[4*e+0], a[4*e+1]);
        u[2*e+1] = cvtpk_bf16(a[4*e+2], a[4*e+3]);
    }
    #pragma unroll
    for (int be = 0; be < 2; ++be) {
        int a0 = (int)u[4*be+2], b0 = (int)u[4*be+0];
        asm("v_permlane32_swap_b32 %0, %1" : "+v"(a0), "+v"(b0));
        int a1 = (int)u[4*be+3], b1 = (int)u[4*be+1];
        asm("v_permlane32_swap_b32 %0, %1" : "+v"(a1), "+v"(b1));
        union { int i[4]; short8v v; } pu;
        pu.i[0] = b0; pu.i[1] = b1; pu.i[2] = a0; pu.i[3] = a1;
        if (be == 0) f0 = pu.v; else f1 = pu.v;
    }
}

// ---------------- K0: one-shot weight fp32->bf16 conversion ----------------
__global__ __launch_bounds__(512) void wcvt_kernel(
    const float* __restrict__ a0, const float* __restrict__ a1,
    const float* __restrict__ a2, const float* __restrict__ a3,
    const float* __restrict__ a4, u16* __restrict__ dst)
{
    int q = blockIdx.x * 512 + threadIdx.x;   // float4 index, 40960 total
    int i = q * 4;
    const float* src; int off;
    if      (i < 49152)  { src = a0; off = 0; }
    else if (i < 65536)  { src = a1; off = 49152; }
    else if (i < 114688) { src = a2; off = 65536; }
    else if (i < 131072) { src = a3; off = 114688; }
    else                 { src = a4; off = 131072; }
    float4 v = *reinterpret_cast<const float4*>(src + (i - off));
    ushort4 o = { f2b(v.x), f2b(v.y), f2b(v.z), f2b(v.w) };
    *reinterpret_cast<ushort4*>(dst + i) = o;
}

// Stage a 128x128 bf16 weight block into LDS, pitch 136 u16 (272 B).
__device__ __forceinline__ void stage_wb(const u16* __restrict__ Wb,
                                         u16* __restrict__ Wl, int tid) {
    #pragma unroll
    for (int it = 0; it < 4; ++it) {
        int f = tid + it * 512;           // 2048 chunks of 8 u16
        int row = f >> 4, c8 = f & 15;
        uint4 v = *reinterpret_cast<const uint4*>(Wb + (size_t)row * DD + c8 * 8);
        *reinterpret_cast<uint4*>(&Wl[row * 136 + c8 * 8]) = v;
    }
}

// ---------------- K1: fused QKV-projection + attention v3 ----------------
// One block per (head h, row r); XCD-aware decode (4 heads of a row share bid%8).
// ILP-first design: ALL 24 weight fragments are loaded into registers BEFORE the
// X-staging barrier (their ~500cy latency hides under the 128KB stage), so Phase B
// is pure LDS-read + MFMA with no global latency on the critical path.
// launch_bounds(512,2): 256-reg cap, ~1 block/CU -- trading occupancy for ILP.
__global__ __launch_bounds__(512, 2) void fused_qkv_attn(
    const float* __restrict__ Xf, const u16* __restrict__ Xb,
    const u16* __restrict__ Wb, const float* __restrict__ bias,
    __hip_bfloat16* __restrict__ O, int swap_store)
{
    constexpr int XP = 136;   // X_lds pitch (u16)
    constexpr int KP = 40;    // K_lds pitch (u16)
    constexpr int VP = 264;   // Vt pitch (u16)
    __shared__ u16 SMEM[256 * XP];        // 69632 B; X aliased over K+Vt (37376 B)
    u16* X_lds  = SMEM;
    u16* K_lds  = SMEM;
    u16* Vt_lds = SMEM + 256 * KP;

    const int tid = threadIdx.x;
    const int bid = blockIdx.x;
    const int xcd = bid & 7, mm = bid >> 3;
    const int r = xcd * 32 + (mm >> 2);   // all 4 heads of row r share bid%8
    const int h = mm & 3;

    const int lane = tid & 63;
    const int wq = tid >> 6;          // 8 waves; wave owns tokens/queries [32wq, 32wq+32)
    const int ql = lane & 31;
    const int hi = lane >> 5;
    const int t0 = wq * 32;

    // ---- hoisted weight-fragment loads (issued before staging; latency hidden) ----
    const u16* Wq = Wb + (size_t)(h * 32) * DD;
    const u16* Wk = Wb + (size_t)(128 + h * 32) * DD;
    const u16* Wv = Wb + (size_t)(256 + h * 32) * DD;
    short8v wfq[8], wfk[8], wfv[8];
    #pragma unroll
    for (int ks = 0; ks < 8; ++ks) {
        wfq[ks] = *reinterpret_cast<const short8v*>(Wq + (size_t)ql * DD + ks * 16 + hi * 8);
        wfk[ks] = *reinterpret_cast<const short8v*>(Wk + (size_t)ql * DD + ks * 16 + hi * 8);
        wfv[ks] = *reinterpret_cast<const short8v*>(Wv + (size_t)ql * DD + ks * 16 + hi * 8);
    }

    // ---- Phase A: stage X row -> X_lds (bf16) ----
    if (Xb) {
        const u16* xs = Xb + (size_t)r * 256 * DD;
        #pragma unroll
        for (int it = 0; it < 4; ++it) {
            int f = tid + it * 512, row = f >> 4, c8 = f & 15;
            uint4 v = *reinterpret_cast<const uint4*>(xs + row * DD + c8 * 8);
            *reinterpret_cast<uint4*>(&X_lds[row * XP + c8 * 8]) = v;
        }
    } else {
        const float* xs = Xf + (size_t)r * 256 * DD;
        #pragma unroll
        for (int it = 0; it < 16; ++it) {
            int f = tid + it * 512, row = f >> 5, c4 = f & 31;
            float4 v = *reinterpret_cast<const float4*>(xs + row * DD + c4 * 4);
            ushort4 o = { f2b(v.x), f2b(v.y), f2b(v.z), f2b(v.w) };
            *reinterpret_cast<ushort4*>(&X_lds[row * XP + c4 * 4]) = o;
        }
    }
    __syncthreads();

    // ---- Phase B: per-wave QKV projection (X from LDS, W from registers) ----
    floatx16 qa, ka, va;
    #pragma unroll
    for (int k2 = 0; k2 < 4; ++k2) {
        int d0 = 8 * k2 + 4 * hi;
        float4 b1 = *reinterpret_cast<const float4*>(bias + h * 32 + d0);
        float4 b2 = *reinterpret_cast<const float4*>(bias + 128 + h * 32 + d0);
        float4 b3 = *reinterpret_cast<const float4*>(bias + 256 + h * 32 + d0);
        qa[4*k2+0] = b1.x; qa[4*k2+1] = b1.y; qa[4*k2+2] = b1.z; qa[4*k2+3] = b1.w;
        ka[4*k2+0] = b2.x; ka[4*k2+1] = b2.y; ka[4*k2+2] = b2.z; ka[4*k2+3] = b2.w;
        va[4*k2+0] = b3.x; va[4*k2+1] = b3.y; va[4*k2+2] = b3.z; va[4*k2+3] = b3.w;
    }

    #pragma unroll
    for (int ks = 0; ks < 8; ++ks) {
        short8v xb = *reinterpret_cast<const short8v*>(
            &X_lds[(t0 + ql) * XP + ks * 16 + hi * 8]);
        qa = __builtin_amdgcn_mfma_f32_32x32x16_bf16(wfq[ks], xb, qa, 0, 0, 0);
        ka = __builtin_amdgcn_mfma_f32_32x32x16_bf16(wfk[ks], xb, ka, 0, 0, 0);
        va = __builtin_amdgcn_mfma_f32_32x32x16_bf16(wfv[ks], xb, va, 0, 0, 0);
    }

    short8v qf0, qf1, kf0, kf1;
    repack16(qa, qf0, qf1);     // Q stays in registers (this wave consumes it)
    repack16(ka, kf0, kf1);

    __syncthreads();            // all X_lds reads done; safe to overwrite (aliased)

    *reinterpret_cast<uint4*>(&K_lds[(t0 + ql) * KP + hi * 8]) =
        *reinterpret_cast<const uint4*>(&kf0);
    *reinterpret_cast<uint4*>(&K_lds[(t0 + ql) * KP + 16 + hi * 8]) =
        *reinterpret_cast<const uint4*>(&kf1);
    #pragma unroll
    for (int rr = 0; rr < 16; ++rr)
        Vt_lds[((rr & 3) + 8 * (rr >> 2) + 4 * hi) * VP + t0 + ql] = f2b(va[rr]);
    __syncthreads();

    // ---- Phase C: attention (streaming softmax, permlane-only cross-lane) ----
    const float C1 = 0.25505654196988f;   // (1/sqrt(32)) * log2(e)
    const floatx16 zf = {0.f,0.f,0.f,0.f,0.f,0.f,0.f,0.f,
                         0.f,0.f,0.f,0.f,0.f,0.f,0.f,0.f};

    floatx16 acc0 = zf, acc1 = zf;   // dual PV accumulators (halve serial chain)
    float ell = 0.f;

    __builtin_amdgcn_s_setprio(1);
    #pragma unroll
    for (int b = 0; b < 8; ++b) {
        // ---- QK^T for this 32-k block ----
        short8v k0 = *reinterpret_cast<const short8v*>(&K_lds[(32 * b + ql) * KP + hi * 8]);
        short8v k1 = *reinterpret_cast<const short8v*>(&K_lds[(32 * b + ql) * KP + 16 + hi * 8]);
        floatx16 s = zf;
        s = __builtin_amdgcn_mfma_f32_32x32x16_bf16(k0, qf0, s, 0, 0, 0);
        s = __builtin_amdgcn_mfma_f32_32x32x16_bf16(k1, qf1, s, 0, 0, 0);

        // ---- exp2 (no max shift; |S*C1| << 30) + pack to bf16 pairs ----
        unsigned u[8];
        #pragma unroll
        for (int e = 0; e < 4; ++e) {
            float p0 = __builtin_amdgcn_exp2f(s[4*e+0] * C1);
            float p1 = __builtin_amdgcn_exp2f(s[4*e+1] * C1);
            float p2 = __builtin_amdgcn_exp2f(s[4*e+2] * C1);
            float p3 = __builtin_amdgcn_exp2f(s[4*e+3] * C1);
            ell += (p0 + p1) + (p2 + p3);
            u[2*e]     = cvtpk_bf16(p0, p1);
            u[2*e + 1] = cvtpk_bf16(p2, p3);
        }

        // ---- PV for the two 16-k halves (even->acc0, odd->acc1) ----
        #pragma unroll
        for (int be = 0; be < 2; ++be) {
            const int kb = 2 * b + be;
            int a0 = (int)u[4*be + 2], b0 = (int)u[4*be + 0];
            asm("v_permlane32_swap_b32 %0, %1" : "+v"(a0), "+v"(b0));
            int a1 = (int)u[4*be + 3], b1 = (int)u[4*be + 1];
            asm("v_permlane32_swap_b32 %0, %1" : "+v"(a1), "+v"(b1));
            union { int i[4]; short8v v; } pu;
            pu.i[0] = b0; pu.i[1] = b1; pu.i[2] = a0; pu.i[3] = a1;
            short8v vf = *reinterpret_cast<const short8v*>(&Vt_lds[ql * VP + kb * 16 + hi * 8]);
            if (be == 0)
                acc0 = __builtin_amdgcn_mfma_f32_32x32x16_bf16(vf, pu.v, acc0, 0, 0, 0);
            else
                acc1 = __builtin_amdgcn_mfma_f32_32x32x16_bf16(vf, pu.v, acc1, 0, 0, 0);
        }
    }
    __builtin_amdgcn_s_setprio(0);

    // ---- ell reduce across hi halves (lane <-> lane+32) ----
    {
        float ex = ell, ey = ell;
        asm("v_permlane32_swap_b32 %0, %1" : "+v"(ex), "+v"(ey));
        ell = ex + ey;
    }

    // ---- store: lane holds d = (rr&3)+8(rr>>2)+4hi for q = t0+ql ----
    const float inv = 1.f / ell;
    const int q = t0 + ql;
    const size_t opos = swap_store ? ((size_t)q * 256 + r) : ((size_t)r * 256 + q);
    u16* ob = reinterpret_cast<u16*>(O) + (size_t)h * 2097152 + opos * 32;
    #pragma unroll
    for (int e = 0; e < 4; ++e) {
        ushort4 w = { f2b((acc0[4*e+0] + acc1[4*e+0]) * inv),
                      f2b((acc0[4*e+1] + acc1[4*e+1]) * inv),
                      f2b((acc0[4*e+2] + acc1[4*e+2]) * inv),
                      f2b((acc0[4*e+3] + acc1[4*e+3]) * inv) };
        *reinterpret_cast<ushort4*>(ob + e * 8 + hi * 4) = w;
    }
}

// ---------------- K3: out-proj + bias + residual + LN (phase 1) ----------
// A is head-major [4][65536][32]. Writes: RESb (bf16, normal order; phase-2
// residual) and Xt (bf16 transposed; phase-2 fused input).
__global__ __launch_bounds__(512) void proj_ln_mfma(
    const __hip_bfloat16* __restrict__ A, const u16* __restrict__ Wb,
    const float* __restrict__ bias, const float* __restrict__ RES,
    const float* __restrict__ gamma, const float* __restrict__ beta,
    u16* __restrict__ RESb, u16* __restrict__ Xt)
{
    __shared__ u16 Wl[128 * 136];
    const int tid = threadIdx.x;
    const int tok0 = blockIdx.x * 128;
    const int lane = tid & 63, wq = tid >> 6;
    const int lq = lane & 15, g = lane >> 4;
    const int t = tok0 + wq * 16 + lq;
    const u16* A16 = reinterpret_cast<const u16*>(A);

    stage_wb(Wb, Wl, tid);

    short8v bfrag[4];
    #pragma unroll
    for (int ks = 0; ks < 4; ++ks)
        bfrag[ks] = *reinterpret_cast<const short8v*>(
            A16 + (size_t)ks * 2097152 + (size_t)t * 32 + g * 8);

    __syncthreads();

    floatx4 acc[8];
    #pragma unroll
    for (int et = 0; et < 8; ++et) {
        float4 b4 = *reinterpret_cast<const float4*>(bias + et * 16 + g * 4);
        float4 r4 = *reinterpret_cast<const float4*>(RES + (size_t)t * DD + et * 16 + g * 4);
        acc[et] = { b4.x + r4.x, b4.y + r4.y, b4.z + r4.z, b4.w + r4.w };
        #pragma unroll
        for (int ks = 0; ks < 4; ++ks) {
            short8v afrag = *reinterpret_cast<const short8v*>(
                &Wl[(et * 16 + lq) * 136 + ks * 32 + g * 8]);
            acc[et] = __builtin_amdgcn_mfma_f32_16x16x32_bf16(afrag, bfrag[ks], acc[et], 0, 0, 0);
        }
    }

    float s = 0.f, ss = 0.f;
    #pragma unroll
    for (int et = 0; et < 8; ++et)
        #pragma unroll
        for (int rr = 0; rr < 4; ++rr) { float v = acc[et][rr]; s += v; ss += v * v; }
    s  += __shfl_xor(s, 16);  s  += __shfl_xor(s, 32);
    ss += __shfl_xor(ss, 16); ss += __shfl_xor(ss, 32);
    float mu = s * (1.f / 128.f);
    float var = ss * (1.f / 128.f) - mu * mu;
    float rstd = rsqrtf(var + 1e-5f);

    u16* xt = Xt + (size_t)((t & 255) * 256 + (t >> 8)) * DD;
    u16* rb = RESb + (size_t)t * DD;
    #pragma unroll
    for (int et = 0; et < 8; ++et) {
        float4 g4 = *reinterpret_cast<const float4*>(gamma + et * 16 + g * 4);
        float4 be4 = *reinterpret_cast<const float4*>(beta + et * 16 + g * 4);
        float4 o4;
        o4.x = (acc[et][0] - mu) * rstd * g4.x + be4.x;
        o4.y = (acc[et][1] - mu) * rstd * g4.y + be4.y;
        o4.z = (acc[et][2] - mu) * rstd * g4.z + be4.z;
        o4.w = (acc[et][3] - mu) * rstd * g4.w + be4.w;
        ushort4 xb = { f2b(o4.x), f2b(o4.y), f2b(o4.z), f2b(o4.w) };
        *reinterpret_cast<ushort4*>(&xt[et * 16 + g * 4]) = xb;
        *reinterpret_cast<ushort4*>(&rb[et * 16 + g * 4]) = xb;
    }
}

// ---------------- K3b: out-proj + LN + gate fused (phase 2 epilogue) ----------
__global__ __launch_bounds__(512) void proj_ln_gate_mfma(
    const __hip_bfloat16* __restrict__ A, const u16* __restrict__ Wb,
    const float* __restrict__ bias, const u16* __restrict__ RESb,
    const float* __restrict__ gamma, const float* __restrict__ beta,
    const u16* __restrict__ Wgb, const float* __restrict__ bg,
    float* __restrict__ OUT)
{
    __shared__ u16 Wl[128 * 136];   // Wout, later overwritten with Wg
    __shared__ u16 Yl[128 * 136];   // y (bf16), token-major
    const int tid = threadIdx.x;
    const int tok0 = blockIdx.x * 128;
    const int lane = tid & 63, wq = tid >> 6;
    const int lq = lane & 15, g = lane >> 4;
    const int tl = wq * 16 + lq;
    const int t = tok0 + tl;
    const u16* A16 = reinterpret_cast<const u16*>(A);

    stage_wb(Wb, Wl, tid);

    short8v bfrag[4];
    #pragma unroll
    for (int ks = 0; ks < 4; ++ks)
        bfrag[ks] = *reinterpret_cast<const short8v*>(
            A16 + (size_t)ks * 2097152 + (size_t)t * 32 + g * 8);

    __syncthreads();

    floatx4 acc[8];
    #pragma unroll
    for (int et = 0; et < 8; ++et) {
        float4 b4 = *reinterpret_cast<const float4*>(bias + et * 16 + g * 4);
        ushort4 rv = *reinterpret_cast<const ushort4*>(RESb + (size_t)t * DD + et * 16 + g * 4);
        acc[et] = { b4.x + bf2f(rv.x), b4.y + bf2f(rv.y),
                    b4.z + bf2f(rv.z), b4.w + bf2f(rv.w) };
        #pragma unroll
        for (int ks = 0; ks < 4; ++ks) {
            short8v afrag = *reinterpret_cast<const short8v*>(
                &Wl[(et * 16 + lq) * 136 + ks * 32 + g * 8]);
            acc[et] = __builtin_amdgcn_mfma_f32_16x16x32_bf16(afrag, bfrag[ks], acc[et], 0, 0, 0);
        }
    }

    float s = 0.f, ss = 0.f;
    #pragma unroll
    for (int et = 0; et < 8; ++et)
        #pragma unroll
        for (int rr = 0; rr < 4; ++rr) { float v = acc[et][rr]; s += v; ss += v * v; }
    s  += __shfl_xor(s, 16);  s  += __shfl_xor(s, 32);
    ss += __shfl_xor(ss, 16); ss += __shfl_xor(ss, 32);
    float mu = s * (1.f / 128.f);
    float var = ss * (1.f / 128.f) - mu * mu;
    float rstd = rsqrtf(var + 1e-5f);

    #pragma unroll
    for (int et = 0; et < 8; ++et) {
        float4 g4 = *reinterpret_cast<const float4*>(gamma + et * 16 + g * 4);
        float4 be4 = *reinterpret_cast<const float4*>(beta + et * 16 + g * 4);
        acc[et][0] = (acc[et][0] - mu) * rstd * g4.x + be4.x;
        acc[et][1] = (acc[et][1] - mu) * rstd * g4.y + be4.y;
        acc[et][2] = (acc[et][2] - mu) * rstd * g4.z + be4.z;
        acc[et][3] = (acc[et][3] - mu) * rstd * g4.w + be4.w;
        ushort4 yb;
        yb.x = f2b(acc[et][0]); yb.y = f2b(acc[et][1]);
        yb.z = f2b(acc[et][2]); yb.w = f2b(acc[et][3]);
        *reinterpret_cast<ushort4*>(&Yl[tl * 136 + et * 16 + g * 4]) = yb;
    }

    __syncthreads();               // Yl complete; Wl reads done
    stage_wb(Wgb, Wl, tid);        // overwrite Wl with gate weights
    __syncthreads();

    short8v yfrag[4];
    #pragma unroll
    for (int ks = 0; ks < 4; ++ks)
        yfrag[ks] = *reinterpret_cast<const short8v*>(&Yl[tl * 136 + ks * 32 + g * 8]);

    #pragma unroll
    for (int et = 0; et < 8; ++et) {
        float4 b4 = *reinterpret_cast<const float4*>(bg + et * 16 + g * 4);
        floatx4 z = { b4.x, b4.y, b4.z, b4.w };
        #pragma unroll
        for (int ks = 0; ks < 4; ++ks) {
            short8v afrag = *reinterpret_cast<const short8v*>(
                &Wl[(et * 16 + lq) * 136 + ks * 32 + g * 8]);
            z = __builtin_amdgcn_mfma_f32_16x16x32_bf16(afrag, yfrag[ks], z, 0, 0, 0);
        }
        float4 o4;
        o4.x = acc[et][0] / (1.f + __expf(-z[0]));
        o4.y = acc[et][1] / (1.f + __expf(-z[1]));
        o4.z = acc[et][2] / (1.f + __expf(-z[2]));
        o4.w = acc[et][3] / (1.f + __expf(-z[3]));
        *reinterpret_cast<float4*>(OUT + (size_t)t * DD + et * 16 + g * 4) = o4;
    }
}

extern "C" void kernel_launch(void* const* d_in, const int* in_sizes, int n_in,
                              void* d_out, int out_size, void* d_ws, size_t ws_size,
                              hipStream_t stream) {
    const float* pair    = (const float*)d_in[0];
    const float* w_in_s  = (const float*)d_in[2];
    const float* b_in_s  = (const float*)d_in[3];
    const float* w_out_s = (const float*)d_in[4];
    const float* b_out_s = (const float*)d_in[5];
    const float* w_in_e  = (const float*)d_in[6];
    const float* b_in_e  = (const float*)d_in[7];
    const float* w_out_e = (const float*)d_in[8];
    const float* b_out_e = (const float*)d_in[9];
    const float* gamma_s = (const float*)d_in[10];
    const float* beta_s  = (const float*)d_in[11];
    const float* gamma_e = (const float*)d_in[12];
    const float* beta_e  = (const float*)d_in[13];
    const float* w_gate  = (const float*)d_in[14];
    const float* b_gate  = (const float*)d_in[15];
    float* out = (float*)d_out;

    // workspace: attn-out [4][65536][32] 16Mi | Xt 16Mi | RESb 16Mi | Wbf16 288Ki
    __hip_bfloat16* attn = (__hip_bfloat16*)d_ws;
    u16*            xt   = (u16*)(attn + (size_t)65536 * 128);
    u16*            resb = xt + (size_t)65536 * 128;
    u16*            wb   = resb + (size_t)65536 * 128;
    // wb u16 offsets: in_s 0 | out_s 49152 | in_e 65536 | out_e 114688 | gate 131072

    wcvt_kernel<<<80, 512, 0, stream>>>(w_in_s, w_out_s, w_in_e, w_out_e, w_gate, wb);

    // ---- phase 1: row-wise (starting node) attention ----
    fused_qkv_attn<<<1024, 512, 0, stream>>>(pair, nullptr, wb, b_in_s, attn, 0);
    proj_ln_mfma<<<512, 512, 0, stream>>>(attn, wb + 49152, b_out_s, pair,
                                          gamma_s, beta_s, resb, xt);
    // ---- phase 2: column-wise (ending node) attention + fused gate ----
    fused_qkv_attn<<<1024, 512, 0, stream>>>(nullptr, xt, wb + 65536, b_in_e, attn, 1);
    proj_ln_gate_mfma<<<512, 512, 0, stream>>>(attn, wb + 114688, b_out_e, resb,
                                               gamma_e, beta_e, wb + 131072, b_gate,
                                               out);
}

// Round 14
// 125.554 us; speedup vs baseline: 1.2479x; 1.2479x over previous
//
#include <hip/hip_runtime.h>
#include <hip/hip_bf16.h>
#include <cstddef>

// Problem constants: B=1, L=256, D=128, H=4, hd=32
#define DD 128

typedef unsigned short u16;
typedef short short8v __attribute__((ext_vector_type(8)));    // 8 bf16 (4 VGPRs)
typedef float floatx4 __attribute__((ext_vector_type(4)));    // 4 fp32 acc
typedef float floatx16 __attribute__((ext_vector_type(16)));  // 16 fp32 acc (32x32)

__device__ __forceinline__ float bf2f(u16 u) {
    return __uint_as_float(((unsigned int)u) << 16);
}
__device__ __forceinline__ u16 f2b(float x) {   // round-to-nearest-even f32->bf16
    unsigned u = __float_as_uint(x);
    return (u16)((u + 0x7FFF + ((u >> 16) & 1)) >> 16);
}
__device__ __forceinline__ unsigned cvtpk_bf16(float lo, float hi) {
    unsigned r;
    asm("v_cvt_pk_bf16_f32 %0, %1, %2" : "=v"(r) : "v"(lo), "v"(hi));
    return r;
}

// Repack a 32x32 MFMA D-tile (lane=col, 16 rows at (rr&3)+8*(rr>>2)+4*hi) into two
// operand fragments (lane-local rows 8hi..8hi+7 per 16-row half) -- verified
// cvt_pk + permlane32_swap algebra (same as the attention P repack).
__device__ __forceinline__ void repack16(const floatx16& a, short8v& f0, short8v& f1) {
    unsigned u[8];
    #pragma unroll
    for (int e = 0; e < 4; ++e) {
        u[2*e]   = cvtpk_bf16(a[4*e+0], a[4*e+1]);
        u[2*e+1] = cvtpk_bf16(a[4*e+2], a[4*e+3]);
    }
    #pragma unroll
    for (int be = 0; be < 2; ++be) {
        int a0 = (int)u[4*be+2], b0 = (int)u[4*be+0];
        asm("v_permlane32_swap_b32 %0, %1" : "+v"(a0), "+v"(b0));
        int a1 = (int)u[4*be+3], b1 = (int)u[4*be+1];
        asm("v_permlane32_swap_b32 %0, %1" : "+v"(a1), "+v"(b1));
        union { int i[4]; short8v v; } pu;
        pu.i[0] = b0; pu.i[1] = b1; pu.i[2] = a0; pu.i[3] = a1;
        if (be == 0) f0 = pu.v; else f1 = pu.v;
    }
}

// ---------------- K0: one-shot weight fp32->bf16 conversion ----------------
__global__ __launch_bounds__(512) void wcvt_kernel(
    const float* __restrict__ a0, const float* __restrict__ a1,
    const float* __restrict__ a2, const float* __restrict__ a3,
    const float* __restrict__ a4, u16* __restrict__ dst)
{
    int q = blockIdx.x * 512 + threadIdx.x;   // float4 index, 40960 total
    int i = q * 4;
    const float* src; int off;
    if      (i < 49152)  { src = a0; off = 0; }
    else if (i < 65536)  { src = a1; off = 49152; }
    else if (i < 114688) { src = a2; off = 65536; }
    else if (i < 131072) { src = a3; off = 114688; }
    else                 { src = a4; off = 131072; }
    float4 v = *reinterpret_cast<const float4*>(src + (i - off));
    ushort4 o = { f2b(v.x), f2b(v.y), f2b(v.z), f2b(v.w) };
    *reinterpret_cast<ushort4*>(dst + i) = o;
}

// Stage a 128x128 bf16 weight block into LDS, pitch 136 u16 (272 B).
__device__ __forceinline__ void stage_wb(const u16* __restrict__ Wb,
                                         u16* __restrict__ Wl, int tid) {
    #pragma unroll
    for (int it = 0; it < 4; ++it) {
        int f = tid + it * 512;           // 2048 chunks of 8 u16
        int row = f >> 4, c8 = f & 15;
        uint4 v = *reinterpret_cast<const uint4*>(Wb + (size_t)row * DD + c8 * 8);
        *reinterpret_cast<uint4*>(&Wl[row * 136 + c8 * 8]) = v;
    }
}

// ---------------- K1: fused QKV-projection + attention (r11 base + C-pipeline) ----
// One block per (head h, row r); XCD-aware decode (4 heads of a row share bid%8).
// Phase A: stage X row (256x128) to LDS bf16 (aliased over K/Vt, barrier-separated).
// Phase B: wave projects its 32 tokens (Q regs via repack, K->LDS, V->LDS transposed).
// Phase C: streaming-softmax attention, 2-deep software pipeline: QK^T of block b+1
// issues while the VALU runs exp/pack/PV of block b (named sEven/sOdd, static idx);
// dual PV accumulators halve the MFMA accumulate chain.
__global__ __launch_bounds__(512, 4) void fused_qkv_attn(
    const float* __restrict__ Xf, const u16* __restrict__ Xb,
    const u16* __restrict__ Wb, const float* __restrict__ bias,
    __hip_bfloat16* __restrict__ O, int swap_store)
{
    constexpr int XP = 136;   // X_lds pitch (u16)
    constexpr int KP = 40;    // K_lds pitch (u16)
    constexpr int VP = 264;   // Vt pitch (u16)
    __shared__ u16 SMEM[256 * XP];        // 69632 B; X aliased over K+Vt (37376 B)
    u16* X_lds  = SMEM;
    u16* K_lds  = SMEM;
    u16* Vt_lds = SMEM + 256 * KP;

    const int tid = threadIdx.x;
    const int bid = blockIdx.x;
    const int xcd = bid & 7, mm = bid >> 3;
    const int r = xcd * 32 + (mm >> 2);   // all 4 heads of row r share bid%8
    const int h = mm & 3;

    // ---- Phase A: stage X row -> X_lds (bf16) ----
    if (Xb) {
        const u16* xs = Xb + (size_t)r * 256 * DD;
        #pragma unroll
        for (int it = 0; it < 4; ++it) {
            int f = tid + it * 512, row = f >> 4, c8 = f & 15;
            uint4 v = *reinterpret_cast<const uint4*>(xs + row * DD + c8 * 8);
            *reinterpret_cast<uint4*>(&X_lds[row * XP + c8 * 8]) = v;
        }
    } else {
        const float* xs = Xf + (size_t)r * 256 * DD;
        #pragma unroll
        for (int it = 0; it < 16; ++it) {
            int f = tid + it * 512, row = f >> 5, c4 = f & 31;
            float4 v = *reinterpret_cast<const float4*>(xs + row * DD + c4 * 4);
            ushort4 o = { f2b(v.x), f2b(v.y), f2b(v.z), f2b(v.w) };
            *reinterpret_cast<ushort4*>(&X_lds[row * XP + c4 * 4]) = o;
        }
    }
    __syncthreads();

    const int lane = tid & 63;
    const int wq = tid >> 6;          // 8 waves; wave owns tokens/queries [32wq, 32wq+32)
    const int ql = lane & 31;
    const int hi = lane >> 5;
    const int t0 = wq * 32;

    // ---- Phase B: per-wave QKV projection ----
    const u16* Wq = Wb + (size_t)(h * 32) * DD;
    const u16* Wk = Wb + (size_t)(128 + h * 32) * DD;
    const u16* Wv = Wb + (size_t)(256 + h * 32) * DD;

    floatx16 qa, ka, va;
    #pragma unroll
    for (int k2 = 0; k2 < 4; ++k2) {
        int d0 = 8 * k2 + 4 * hi;
        float4 b1 = *reinterpret_cast<const float4*>(bias + h * 32 + d0);
        float4 b2 = *reinterpret_cast<const float4*>(bias + 128 + h * 32 + d0);
        float4 b3 = *reinterpret_cast<const float4*>(bias + 256 + h * 32 + d0);
        qa[4*k2+0] = b1.x; qa[4*k2+1] = b1.y; qa[4*k2+2] = b1.z; qa[4*k2+3] = b1.w;
        ka[4*k2+0] = b2.x; ka[4*k2+1] = b2.y; ka[4*k2+2] = b2.z; ka[4*k2+3] = b2.w;
        va[4*k2+0] = b3.x; va[4*k2+1] = b3.y; va[4*k2+2] = b3.z; va[4*k2+3] = b3.w;
    }

    #pragma unroll
    for (int ks = 0; ks < 8; ++ks) {
        short8v xb = *reinterpret_cast<const short8v*>(
            &X_lds[(t0 + ql) * XP + ks * 16 + hi * 8]);
        short8v aq = *reinterpret_cast<const short8v*>(Wq + (size_t)ql * DD + ks * 16 + hi * 8);
        short8v ak = *reinterpret_cast<const short8v*>(Wk + (size_t)ql * DD + ks * 16 + hi * 8);
        short8v av = *reinterpret_cast<const short8v*>(Wv + (size_t)ql * DD + ks * 16 + hi * 8);
        qa = __builtin_amdgcn_mfma_f32_32x32x16_bf16(aq, xb, qa, 0, 0, 0);
        ka = __builtin_amdgcn_mfma_f32_32x32x16_bf16(ak, xb, ka, 0, 0, 0);
        va = __builtin_amdgcn_mfma_f32_32x32x16_bf16(av, xb, va, 0, 0, 0);
    }

    short8v qf0, qf1, kf0, kf1;
    repack16(qa, qf0, qf1);     // Q stays in registers (this wave consumes it)
    repack16(ka, kf0, kf1);

    __syncthreads();            // all X_lds reads done; safe to overwrite (aliased)

    *reinterpret_cast<uint4*>(&K_lds[(t0 + ql) * KP + hi * 8]) =
        *reinterpret_cast<const uint4*>(&kf0);
    *reinterpret_cast<uint4*>(&K_lds[(t0 + ql) * KP + 16 + hi * 8]) =
        *reinterpret_cast<const uint4*>(&kf1);
    #pragma unroll
    for (int rr = 0; rr < 16; ++rr)
        Vt_lds[((rr & 3) + 8 * (rr >> 2) + 4 * hi) * VP + t0 + ql] = f2b(va[rr]);
    __syncthreads();

    // ---- Phase C: attention (streaming softmax, 2-deep pipeline) ----
    const float C1 = 0.25505654196988f;   // (1/sqrt(32)) * log2(e)
    const floatx16 zf = {0.f,0.f,0.f,0.f,0.f,0.f,0.f,0.f,
                         0.f,0.f,0.f,0.f,0.f,0.f,0.f,0.f};

    floatx16 acc0 = zf, acc1 = zf;   // dual PV accumulators (halve serial chain)
    float ell = 0.f;

    auto qk_block = [&](int b) -> floatx16 {
        short8v k0 = *reinterpret_cast<const short8v*>(&K_lds[(32 * b + ql) * KP + hi * 8]);
        short8v k1 = *reinterpret_cast<const short8v*>(&K_lds[(32 * b + ql) * KP + 16 + hi * 8]);
        floatx16 s = zf;
        s = __builtin_amdgcn_mfma_f32_32x32x16_bf16(k0, qf0, s, 0, 0, 0);
        s = __builtin_amdgcn_mfma_f32_32x32x16_bf16(k1, qf1, s, 0, 0, 0);
        return s;
    };
    auto process = [&](const floatx16& s, int b) {
        unsigned u[8];
        #pragma unroll
        for (int e = 0; e < 4; ++e) {
            float p0 = __builtin_amdgcn_exp2f(s[4*e+0] * C1);
            float p1 = __builtin_amdgcn_exp2f(s[4*e+1] * C1);
            float p2 = __builtin_amdgcn_exp2f(s[4*e+2] * C1);
            float p3 = __builtin_amdgcn_exp2f(s[4*e+3] * C1);
            ell += (p0 + p1) + (p2 + p3);
            u[2*e]     = cvtpk_bf16(p0, p1);
            u[2*e + 1] = cvtpk_bf16(p2, p3);
        }
        #pragma unroll
        for (int be = 0; be < 2; ++be) {
            const int kb = 2 * b + be;
            int a0 = (int)u[4*be + 2], b0 = (int)u[4*be + 0];
            asm("v_permlane32_swap_b32 %0, %1" : "+v"(a0), "+v"(b0));
            int a1 = (int)u[4*be + 3], b1 = (int)u[4*be + 1];
            asm("v_permlane32_swap_b32 %0, %1" : "+v"(a1), "+v"(b1));
            union { int i[4]; short8v v; } pu;
            pu.i[0] = b0; pu.i[1] = b1; pu.i[2] = a0; pu.i[3] = a1;
            short8v vf = *reinterpret_cast<const short8v*>(&Vt_lds[ql * VP + kb * 16 + hi * 8]);
            if (be == 0)
                acc0 = __builtin_amdgcn_mfma_f32_32x32x16_bf16(vf, pu.v, acc0, 0, 0, 0);
            else
                acc1 = __builtin_amdgcn_mfma_f32_32x32x16_bf16(vf, pu.v, acc1, 0, 0, 0);
        }
    };

    __builtin_amdgcn_s_setprio(1);
    // 2-deep pipeline over the 8 k-blocks: QK(b+1) issues while process(b) runs.
    floatx16 sEven = qk_block(0);
    #pragma unroll
    for (int b = 0; b < 8; b += 2) {
        floatx16 sOdd = qk_block(b + 1);
        process(sEven, b);
        if (b + 2 < 8) sEven = qk_block(b + 2);
        process(sOdd, b + 1);
    }
    __builtin_amdgcn_s_setprio(0);

    // ---- ell reduce across hi halves (lane <-> lane+32) ----
    {
        float ex = ell, ey = ell;
        asm("v_permlane32_swap_b32 %0, %1" : "+v"(ex), "+v"(ey));
        ell = ex + ey;
    }

    // ---- store: lane holds d = (rr&3)+8(rr>>2)+4hi for q = t0+ql ----
    const float inv = 1.f / ell;
    const int q = t0 + ql;
    const size_t opos = swap_store ? ((size_t)q * 256 + r) : ((size_t)r * 256 + q);
    u16* ob = reinterpret_cast<u16*>(O) + (size_t)h * 2097152 + opos * 32;
    #pragma unroll
    for (int e = 0; e < 4; ++e) {
        ushort4 w = { f2b((acc0[4*e+0] + acc1[4*e+0]) * inv),
                      f2b((acc0[4*e+1] + acc1[4*e+1]) * inv),
                      f2b((acc0[4*e+2] + acc1[4*e+2]) * inv),
                      f2b((acc0[4*e+3] + acc1[4*e+3]) * inv) };
        *reinterpret_cast<ushort4*>(ob + e * 8 + hi * 4) = w;
    }
}

// ---------------- K3: out-proj + bias + residual + LN (phase 1) ----------
// A is head-major [4][65536][32]. Writes: RESb (bf16, normal order; phase-2
// residual) and Xt (bf16 transposed; phase-2 fused input).
__global__ __launch_bounds__(512) void proj_ln_mfma(
    const __hip_bfloat16* __restrict__ A, const u16* __restrict__ Wb,
    const float* __restrict__ bias, const float* __restrict__ RES,
    const float* __restrict__ gamma, const float* __restrict__ beta,
    u16* __restrict__ RESb, u16* __restrict__ Xt)
{
    __shared__ u16 Wl[128 * 136];
    const int tid = threadIdx.x;
    const int tok0 = blockIdx.x * 128;
    const int lane = tid & 63, wq = tid >> 6;
    const int lq = lane & 15, g = lane >> 4;
    const int t = tok0 + wq * 16 + lq;
    const u16* A16 = reinterpret_cast<const u16*>(A);

    stage_wb(Wb, Wl, tid);

    short8v bfrag[4];
    #pragma unroll
    for (int ks = 0; ks < 4; ++ks)
        bfrag[ks] = *reinterpret_cast<const short8v*>(
            A16 + (size_t)ks * 2097152 + (size_t)t * 32 + g * 8);

    __syncthreads();

    floatx4 acc[8];
    #pragma unroll
    for (int et = 0; et < 8; ++et) {
        float4 b4 = *reinterpret_cast<const float4*>(bias + et * 16 + g * 4);
        float4 r4 = *reinterpret_cast<const float4*>(RES + (size_t)t * DD + et * 16 + g * 4);
        acc[et] = { b4.x + r4.x, b4.y + r4.y, b4.z + r4.z, b4.w + r4.w };
        #pragma unroll
        for (int ks = 0; ks < 4; ++ks) {
            short8v afrag = *reinterpret_cast<const short8v*>(
                &Wl[(et * 16 + lq) * 136 + ks * 32 + g * 8]);
            acc[et] = __builtin_amdgcn_mfma_f32_16x16x32_bf16(afrag, bfrag[ks], acc[et], 0, 0, 0);
        }
    }

    float s = 0.f, ss = 0.f;
    #pragma unroll
    for (int et = 0; et < 8; ++et)
        #pragma unroll
        for (int rr = 0; rr < 4; ++rr) { float v = acc[et][rr]; s += v; ss += v * v; }
    s  += __shfl_xor(s, 16);  s  += __shfl_xor(s, 32);
    ss += __shfl_xor(ss, 16); ss += __shfl_xor(ss, 32);
    float mu = s * (1.f / 128.f);
    float var = ss * (1.f / 128.f) - mu * mu;
    float rstd = rsqrtf(var + 1e-5f);

    u16* xt = Xt + (size_t)((t & 255) * 256 + (t >> 8)) * DD;
    u16* rb = RESb + (size_t)t * DD;
    #pragma unroll
    for (int et = 0; et < 8; ++et) {
        float4 g4 = *reinterpret_cast<const float4*>(gamma + et * 16 + g * 4);
        float4 be4 = *reinterpret_cast<const float4*>(beta + et * 16 + g * 4);
        float4 o4;
        o4.x = (acc[et][0] - mu) * rstd * g4.x + be4.x;
        o4.y = (acc[et][1] - mu) * rstd * g4.y + be4.y;
        o4.z = (acc[et][2] - mu) * rstd * g4.z + be4.z;
        o4.w = (acc[et][3] - mu) * rstd * g4.w + be4.w;
        ushort4 xb = { f2b(o4.x), f2b(o4.y), f2b(o4.z), f2b(o4.w) };
        *reinterpret_cast<ushort4*>(&xt[et * 16 + g * 4]) = xb;
        *reinterpret_cast<ushort4*>(&rb[et * 16 + g * 4]) = xb;
    }
}

// ---------------- K3b: out-proj + LN + gate fused (phase 2 epilogue) ----------
__global__ __launch_bounds__(512) void proj_ln_gate_mfma(
    const __hip_bfloat16* __restrict__ A, const u16* __restrict__ Wb,
    const float* __restrict__ bias, const u16* __restrict__ RESb,
    const float* __restrict__ gamma, const float* __restrict__ beta,
    const u16* __restrict__ Wgb, const float* __restrict__ bg,
    float* __restrict__ OUT)
{
    __shared__ u16 Wl[128 * 136];   // Wout, later overwritten with Wg
    __shared__ u16 Yl[128 * 136];   // y (bf16), token-major
    const int tid = threadIdx.x;
    const int tok0 = blockIdx.x * 128;
    const int lane = tid & 63, wq = tid >> 6;
    const int lq = lane & 15, g = lane >> 4;
    const int tl = wq * 16 + lq;
    const int t = tok0 + tl;
    const u16* A16 = reinterpret_cast<const u16*>(A);

    stage_wb(Wb, Wl, tid);

    short8v bfrag[4];
    #pragma unroll
    for (int ks = 0; ks < 4; ++ks)
        bfrag[ks] = *reinterpret_cast<const short8v*>(
            A16 + (size_t)ks * 2097152 + (size_t)t * 32 + g * 8);

    __syncthreads();

    floatx4 acc[8];
    #pragma unroll
    for (int et = 0; et < 8; ++et) {
        float4 b4 = *reinterpret_cast<const float4*>(bias + et * 16 + g * 4);
        ushort4 rv = *reinterpret_cast<const ushort4*>(RESb + (size_t)t * DD + et * 16 + g * 4);
        acc[et] = { b4.x + bf2f(rv.x), b4.y + bf2f(rv.y),
                    b4.z + bf2f(rv.z), b4.w + bf2f(rv.w) };
        #pragma unroll
        for (int ks = 0; ks < 4; ++ks) {
            short8v afrag = *reinterpret_cast<const short8v*>(
                &Wl[(et * 16 + lq) * 136 + ks * 32 + g * 8]);
            acc[et] = __builtin_amdgcn_mfma_f32_16x16x32_bf16(afrag, bfrag[ks], acc[et], 0, 0, 0);
        }
    }

    float s = 0.f, ss = 0.f;
    #pragma unroll
    for (int et = 0; et < 8; ++et)
        #pragma unroll
        for (int rr = 0; rr < 4; ++rr) { float v = acc[et][rr]; s += v; ss += v * v; }
    s  += __shfl_xor(s, 16);  s  += __shfl_xor(s, 32);
    ss += __shfl_xor(ss, 16); ss += __shfl_xor(ss, 32);
    float mu = s * (1.f / 128.f);
    float var = ss * (1.f / 128.f) - mu * mu;
    float rstd = rsqrtf(var + 1e-5f);

    #pragma unroll
    for (int et = 0; et < 8; ++et) {
        float4 g4 = *reinterpret_cast<const float4*>(gamma + et * 16 + g * 4);
        float4 be4 = *reinterpret_cast<const float4*>(beta + et * 16 + g * 4);
        acc[et][0] = (acc[et][0] - mu) * rstd * g4.x + be4.x;
        acc[et][1] = (acc[et][1] - mu) * rstd * g4.y + be4.y;
        acc[et][2] = (acc[et][2] - mu) * rstd * g4.z + be4.z;
        acc[et][3] = (acc[et][3] - mu) * rstd * g4.w + be4.w;
        ushort4 yb;
        yb.x = f2b(acc[et][0]); yb.y = f2b(acc[et][1]);
        yb.z = f2b(acc[et][2]); yb.w = f2b(acc[et][3]);
        *reinterpret_cast<ushort4*>(&Yl[tl * 136 + et * 16 + g * 4]) = yb;
    }

    __syncthreads();               // Yl complete; Wl reads done
    stage_wb(Wgb, Wl, tid);        // overwrite Wl with gate weights
    __syncthreads();

    short8v yfrag[4];
    #pragma unroll
    for (int ks = 0; ks < 4; ++ks)
        yfrag[ks] = *reinterpret_cast<const short8v*>(&Yl[tl * 136 + ks * 32 + g * 8]);

    #pragma unroll
    for (int et = 0; et < 8; ++et) {
        float4 b4 = *reinterpret_cast<const float4*>(bg + et * 16 + g * 4);
        floatx4 z = { b4.x, b4.y, b4.z, b4.w };
        #pragma unroll
        for (int ks = 0; ks < 4; ++ks) {
            short8v afrag = *reinterpret_cast<const short8v*>(
                &Wl[(et * 16 + lq) * 136 + ks * 32 + g * 8]);
            z = __builtin_amdgcn_mfma_f32_16x16x32_bf16(afrag, yfrag[ks], z, 0, 0, 0);
        }
        float4 o4;
        o4.x = acc[et][0] / (1.f + __expf(-z[0]));
        o4.y = acc[et][1] / (1.f + __expf(-z[1]));
        o4.z = acc[et][2] / (1.f + __expf(-z[2]));
        o4.w = acc[et][3] / (1.f + __expf(-z[3]));
        *reinterpret_cast<float4*>(OUT + (size_t)t * DD + et * 16 + g * 4) = o4;
    }
}

extern "C" void kernel_launch(void* const* d_in, const int* in_sizes, int n_in,
                              void* d_out, int out_size, void* d_ws, size_t ws_size,
                              hipStream_t stream) {
    const float* pair    = (const float*)d_in[0];
    const float* w_in_s  = (const float*)d_in[2];
    const float* b_in_s  = (const float*)d_in[3];
    const float* w_out_s = (const float*)d_in[4];
    const float* b_out_s = (const float*)d_in[5];
    const float* w_in_e  = (const float*)d_in[6];
    const float* b_in_e  = (const float*)d_in[7];
    const float* w_out_e = (const float*)d_in[8];
    const float* b_out_e = (const float*)d_in[9];
    const float* gamma_s = (const float*)d_in[10];
    const float* beta_s  = (const float*)d_in[11];
    const float* gamma_e = (const float*)d_in[12];
    const float* beta_e  = (const float*)d_in[13];
    const float* w_gate  = (const float*)d_in[14];
    const float* b_gate  = (const float*)d_in[15];
    float* out = (float*)d_out;

    // workspace: attn-out [4][65536][32] 16Mi | Xt 16Mi | RESb 16Mi | Wbf16 288Ki
    __hip_bfloat16* attn = (__hip_bfloat16*)d_ws;
    u16*            xt   = (u16*)(attn + (size_t)65536 * 128);
    u16*            resb = xt + (size_t)65536 * 128;
    u16*            wb   = resb + (size_t)65536 * 128;
    // wb u16 offsets: in_s 0 | out_s 49152 | in_e 65536 | out_e 114688 | gate 131072

    wcvt_kernel<<<80, 512, 0, stream>>>(w_in_s, w_out_s, w_in_e, w_out_e, w_gate, wb);

    // ---- phase 1: row-wise (starting node) attention ----
    fused_qkv_attn<<<1024, 512, 0, stream>>>(pair, nullptr, wb, b_in_s, attn, 0);
    proj_ln_mfma<<<512, 512, 0, stream>>>(attn, wb + 49152, b_out_s, pair,
                                          gamma_s, beta_s, resb, xt);
    // ---- phase 2: column-wise (ending node) attention + fused gate ----
    fused_qkv_attn<<<1024, 512, 0, stream>>>(nullptr, xt, wb + 65536, b_in_e, attn, 1);
    proj_ln_gate_mfma<<<512, 512, 0, stream>>>(attn, wb + 114688, b_out_e, resb,
                                               gamma_e, beta_e, wb + 131072, b_gate,
                                               out);
}